// Round 10
// baseline (108.440 us; speedup 1.0000x reference)
//
#include <hip/hip_runtime.h>

#define ALG_DIM 248
#define ROWS 32                    // rows per main-kernel block
#define KSPLIT 2                   // slices (each stream now owns 2 buckets)
#define KPH 124                    // k-slots per slice (248/2)
#define KPB 62                     // active streams (62 of 64; 2 buckets each)
#define CAP 256                    // uint2 capacity per bucket (pow2; max bucket ~160)
#define CNT_STRIDE 16              // ints between cnt entries (64 B -> spread L2 lines)
#define PLSTRIDE_B 3984            // plane stride bytes (248*16 + 16; /4 = 996 ≡ 4 mod 32)
#define PLSTRIDE_DW 996

typedef __fp16 h2v __attribute__((ext_vector_type(2)));
union H2U { unsigned u; h2v h; };

// ---------- scatter: flat, global-atomic cursors (verified R1/R9 form) ------
// cnt (16 KB) is zeroed by the preceding memset node. packed needs NO
// zero-init: k_main reads exactly [0, sz) per bucket (exact bounds), and
// all speculative reads (discarded prefetch, odd-tail .z/.w never used,
// unconditional tp[0] prime) stay inside the bucket's 128-uint4 allocation.

__global__ void k_scatter(const int* __restrict__ idx_i, const int* __restrict__ idx_j,
                          const int* __restrict__ idx_k, const float* __restrict__ coeff,
                          int* __restrict__ cnt, uint2* __restrict__ packed, int nnz) {
    const int t = blockIdx.x * 256 + threadIdx.x;
    if (t >= nnz) return;
    const int k = idx_k[t];
    const int pos = atomicAdd(&cnt[k * CNT_STRIDE], 1);
    if (pos < CAP) {                           // structurally unreachable guard
        const float c = coeff[t];
        H2U hc; hc.h = __builtin_amdgcn_cvt_pkrtz(c, c);
        uint2 p;
        p.x = ((unsigned)idx_i[t] << 4) | ((unsigned)idx_j[t] << 20);
        p.y = hc.u;
        packed[((size_t)k << 8) + pos] = p;
    }
}

// ---------- main: plane-layout f16 gather, exact bounds, 2 buckets/stream ---
// (core layout + inner loop byte-for-byte R9: verified 105.9 us, 0 conflicts)
// 256 threads = 64 streams x 4 lanes over 32 rows; KSPLIT=2 -> stream S
// gathers buckets p0 = y2*124+S and p0+62 from ONE staged tile (halves the
// x/y staging traffic and per-block overhead vs KSPLIT=4). cnt loads and
// both tp[0] primes issue BEFORE staging -> latency hidden under it.
// Gather loop runs to each lane's OWN bucket size (exec-masked lanes release
// the LDS pipe); odd-triple tail guard; no zero-pad, no wave-max shuffle.

__global__ __launch_bounds__(256, 4) void k_main(
    const float* __restrict__ x, const float* __restrict__ y,
    const uint4* __restrict__ packed4,
    const int* __restrict__ cnt,
    const float* __restrict__ alpha_p, float* __restrict__ out)
{
    __shared__ __align__(16) unsigned xs32[4 * PLSTRIDE_DW];
    __shared__ __align__(16) unsigned ys32[4 * PLSTRIDE_DW];

    const int tid = threadIdx.x;
    const int r0  = blockIdx.x * ROWS;
    const int y2  = blockIdx.y;

    const int S = tid >> 2;                  // stream 0..63
    const int q = tid & 3;                   // my plane (rows 8q..8q+7)
    const bool act = (S < KPB);

    // ---- early loads: sizes + first uint4 of both buckets (hide under staging)
    const int pA = y2 * KPH + ((S < KPB) ? S : 0);
    const int pB = pA + KPB;
    const uint4* tpA = packed4 + ((size_t)pA << 7);
    const uint4* tpB = packed4 + ((size_t)pB << 7);
    const int szA = act ? min(cnt[pA * CNT_STRIDE], CAP) : 0;
    const int szB = act ? min(cnt[pB * CNT_STRIDE], CAP) : 0;
    uint4 primeA = tpA[0];                   // speculative (unused if sz==0)
    uint4 primeB = tpB[0];
    const float alpha = alpha_p[0];

    // ---- staging (unchanged, verified) ----
    for (int u = tid; u < (ALG_DIM / 4) * (ROWS / 2); u += 256) {
        const int rp = u & 15;
        const int cq = u >> 4;
        const size_t ra = (size_t)(r0 + 2 * rp) * ALG_DIM + 4 * cq;
        const float4 xa = *reinterpret_cast<const float4*>(x + ra);
        const float4 xb = *reinterpret_cast<const float4*>(x + ra + ALG_DIM);
        const float4 ya = *reinterpret_cast<const float4*>(y + ra);
        const float4 yb = *reinterpret_cast<const float4*>(y + ra + ALG_DIM);
        const int pbase = (rp >> 2) * PLSTRIDE_DW + (rp & 3);
#define STG(d, XA, XB, YA, YB)                                                  \
        {                                                                       \
            const int dw = pbase + (4 * cq + (d)) * 4;                          \
            H2U hx; hx.h = __builtin_amdgcn_cvt_pkrtz(XA, XB);                  \
            H2U hy; hy.h = __builtin_amdgcn_cvt_pkrtz(YA, YB);                  \
            xs32[dw] = hx.u;                                                    \
            ys32[dw] = hy.u;                                                    \
        }
        STG(0, xa.x, xb.x, ya.x, yb.x)
        STG(1, xa.y, xb.y, ya.y, yb.y)
        STG(2, xa.z, xb.z, ya.z, yb.z)
        STG(3, xa.w, xb.w, ya.w, yb.w)
#undef STG
    }
    __syncthreads();

    const char* xsb = reinterpret_cast<const char*>(xs32) + q * PLSTRIDE_B;
    const char* ysb = reinterpret_cast<const char*>(ys32) + q * PLSTRIDE_B;
    const int rbase = r0 + (q << 3);

#define PROC(PW, PC)                                                            \
        {                                                                       \
            const unsigned ox = (PW) & 0xFFFFu;                                 \
            const unsigned oy = (PW) >> 16;                                     \
            const uint4 wx = *reinterpret_cast<const uint4*>(xsb + ox);         \
            const uint4 wy = *reinterpret_cast<const uint4*>(ysb + oy);         \
            H2U cc; cc.u = (PC);                                                \
            H2U ux, uy;                                                         \
            ux.u = wx.x; uy.u = wy.x; c0 = (ux.h * uy.h) * cc.h + c0;           \
            ux.u = wx.y; uy.u = wy.y; c1 = (ux.h * uy.h) * cc.h + c1;           \
            ux.u = wx.z; uy.u = wy.z; c2 = (ux.h * uy.h) * cc.h + c2;           \
            ux.u = wx.w; uy.u = wy.w; c3 = (ux.h * uy.h) * cc.h + c3;           \
        }
#define FLUSH                                                                   \
        a0 += (float)c0.x; a1 += (float)c0.y;                                   \
        a2 += (float)c1.x; a3 += (float)c1.y;                                   \
        a4 += (float)c2.x; a5 += (float)c2.y;                                   \
        a6 += (float)c3.x; a7 += (float)c3.y;

#define GATHER_STORE(TP, SZ, PRIME, K)                                          \
    if (act) {                                                                  \
        float a0 = 0.f, a1 = 0.f, a2 = 0.f, a3 = 0.f,                           \
              a4 = 0.f, a5 = 0.f, a6 = 0.f, a7 = 0.f;                           \
        const int nFull = (SZ) >> 1;                                            \
        uint4 cur = (PRIME);                                                    \
        for (int chunk = 0; chunk < nFull; chunk += 16) {                       \
            h2v c0 = (h2v)0.0f, c1 = (h2v)0.0f, c2 = (h2v)0.0f, c3 = (h2v)0.0f; \
            const int hend = min(chunk + 16, nFull);                            \
            _Pragma("unroll 2")                                                 \
            for (int h = chunk; h < hend; ++h) {                                \
                const uint4 nxt = (TP)[h + 1];                                  \
                PROC(cur.x, cur.y)                                              \
                PROC(cur.z, cur.w)                                              \
                cur = nxt;                                                      \
            }                                                                   \
            FLUSH                                                               \
        }                                                                       \
        if ((SZ) & 1) {                                                         \
            h2v c0 = (h2v)0.0f, c1 = (h2v)0.0f, c2 = (h2v)0.0f, c3 = (h2v)0.0f; \
            PROC(cur.x, cur.y)                                                  \
            FLUSH                                                               \
        }                                                                       \
        out[(size_t)(rbase + 0) * ALG_DIM + (K)] = alpha * a0;                  \
        out[(size_t)(rbase + 1) * ALG_DIM + (K)] = alpha * a1;                  \
        out[(size_t)(rbase + 2) * ALG_DIM + (K)] = alpha * a2;                  \
        out[(size_t)(rbase + 3) * ALG_DIM + (K)] = alpha * a3;                  \
        out[(size_t)(rbase + 4) * ALG_DIM + (K)] = alpha * a4;                  \
        out[(size_t)(rbase + 5) * ALG_DIM + (K)] = alpha * a5;                  \
        out[(size_t)(rbase + 6) * ALG_DIM + (K)] = alpha * a6;                  \
        out[(size_t)(rbase + 7) * ALG_DIM + (K)] = alpha * a7;                  \
    }

    GATHER_STORE(tpA, szA, primeA, pA)       // bucket 1 (k = pA, identity)
    GATHER_STORE(tpB, szB, primeB, pB)       // bucket 2 (k = pB)

#undef GATHER_STORE
#undef FLUSH
#undef PROC
}

// ---------- launch: 3 nodes (memset is 16 KB cnt only) ----------

extern "C" void kernel_launch(void* const* d_in, const int* in_sizes, int n_in,
                              void* d_out, int out_size, void* d_ws, size_t ws_size,
                              hipStream_t stream) {
    const float* x      = (const float*)d_in[0];
    const float* y      = (const float*)d_in[1];
    const int*   idx_i  = (const int*)d_in[2];
    const int*   idx_j  = (const int*)d_in[3];
    const int*   idx_k  = (const int*)d_in[4];
    const float* coeff  = (const float*)d_in[5];
    const float* alpha  = (const float*)d_in[6];
    float*       out    = (float*)d_out;

    const int nnz   = in_sizes[2];
    const int batch = in_sizes[0] / ALG_DIM;

    // ws: [cnt @0, 16 KB][packed @16384, 248*256*8 = 507904 B, no zero-init]
    char*  ws     = (char*)d_ws;
    int*   cnt    = (int*)ws;
    uint2* packed = (uint2*)(ws + 16384);

    hipMemsetAsync(ws, 0, 16384, stream);                   // cnt only

    k_scatter<<<(nnz + 255) / 256, 256, 0, stream>>>(idx_i, idx_j, idx_k, coeff,
                                                     cnt, packed, nnz);

    dim3 grid(batch / ROWS, KSPLIT);
    k_main<<<grid, 256, 0, stream>>>(x, y, (const uint4*)packed, cnt, alpha, out);
}

// Round 11
// 107.564 us; speedup vs baseline: 1.0081x; 1.0081x over previous
//
#include <hip/hip_runtime.h>

#define ALG_DIM 248
#define ROWS 32                    // rows per main-kernel block
#define KSPLIT 4
#define KPB 62                     // k-slots per block (248/4)
#define CAP 256                    // uint2 capacity per bucket (pow2; max bucket ~160)
#define CNT_STRIDE 16              // ints between cnt entries (64 B -> spread L2 lines)
#define PLSTRIDE_B 3984            // plane stride bytes (248*16 + 16; /4 = 996 ≡ 4 mod 32)
#define PLSTRIDE_DW 996

typedef __fp16 h2v __attribute__((ext_vector_type(2)));
union H2U { unsigned u; h2v h; };

// ---------- scatter: flat, global-atomic cursors, 4 triples/thread ----------
// cnt (16 KB) is zeroed by the preceding memset node. packed needs NO
// zero-init: k_main reads exactly [0, sz) per bucket, and all speculative
// reads (discarded prefetch, odd-tail .z/.w, tp[0] prime) stay inside the
// bucket's 128-uint4 workspace allocation.
// int4/float4 loads (t0 multiple of 4 -> 16B aligned) quarter the load
// instruction count vs the scalar R9 form; atomic count unchanged.

__global__ void k_scatter(const int* __restrict__ idx_i, const int* __restrict__ idx_j,
                          const int* __restrict__ idx_k, const float* __restrict__ coeff,
                          int* __restrict__ cnt, uint2* __restrict__ packed, int nnz) {
    const int t0 = (blockIdx.x * 256 + threadIdx.x) << 2;
    if (t0 >= nnz) return;

#define EMIT(KK, II, JJ, CC)                                                    \
    {                                                                           \
        const int pos = atomicAdd(&cnt[(KK) * CNT_STRIDE], 1);                  \
        if (pos < CAP) {                      /* structurally unreachable */    \
            H2U hc; hc.h = __builtin_amdgcn_cvt_pkrtz((CC), (CC));              \
            uint2 pk;                                                           \
            pk.x = ((unsigned)(II) << 4) | ((unsigned)(JJ) << 20);              \
            pk.y = hc.u;                                                        \
            packed[((size_t)(KK) << 8) + pos] = pk;                             \
        }                                                                       \
    }

    if (t0 + 3 < nnz) {
        const int4   kk = *reinterpret_cast<const int4*>(idx_k + t0);
        const int4   ii = *reinterpret_cast<const int4*>(idx_i + t0);
        const int4   jj = *reinterpret_cast<const int4*>(idx_j + t0);
        const float4 cc = *reinterpret_cast<const float4*>(coeff + t0);
        EMIT(kk.x, ii.x, jj.x, cc.x)
        EMIT(kk.y, ii.y, jj.y, cc.y)
        EMIT(kk.z, ii.z, jj.z, cc.z)
        EMIT(kk.w, ii.w, jj.w, cc.w)
    } else {
        for (int t = t0; t < nnz; ++t)
            EMIT(idx_k[t], idx_i[t], idx_j[t], coeff[t])
    }
#undef EMIT
}

// ---------- main: plane-layout f16 gather, exact per-lane bounds ----------
// (core layout + inner loop byte-for-byte R9: verified 105.9 us, 0 conflicts)
// 256 threads = 64 streams x 4 lanes over 32 rows x 62 slots. x,y in LDS as
// f16 in 4 planes: (col i, rows 8s..8s+7) at byte s*3984 + i*16. Lane q folds
// q*3984 into its base pointer once; gather = ds_read_b128 at base + i*16,
// bank window (i*4 + 4q) mod 32 sweeps all 32 banks as i varies.
// NEW vs R9 (only change): cnt/tp[0]/alpha loads hoisted ABOVE the staging
// loop -> their ~200cy L2 latency completes under staging instead of
// serializing at gather start.

__global__ __launch_bounds__(256, 4) void k_main(
    const float* __restrict__ x, const float* __restrict__ y,
    const uint4* __restrict__ packed4,
    const int* __restrict__ cnt,
    const float* __restrict__ alpha_p, float* __restrict__ out)
{
    __shared__ __align__(16) unsigned xs32[4 * PLSTRIDE_DW];
    __shared__ __align__(16) unsigned ys32[4 * PLSTRIDE_DW];

    const int tid = threadIdx.x;
    const int r0  = blockIdx.x * ROWS;

    const int S   = tid >> 2;                // stream 0..63 (owns one slot)
    const int q   = tid & 3;                 // my plane (rows 8q..8q+7)
    const bool act = (S < KPB);

    // ---- early loads (hide under staging) ----
    const int p  = blockIdx.y * KPB + (act ? S : 0);
    const uint4* tp = packed4 + ((size_t)p << 7);   // 128 uint4 per bucket
    const int sz = act ? min(cnt[p * CNT_STRIDE], CAP) : 0;
    uint4 prime = tp[0];                     // speculative; unused if sz==0
    const float alpha = alpha_p[0];

    // ---- staging (unchanged, verified) ----
    for (int u = tid; u < (ALG_DIM / 4) * (ROWS / 2); u += 256) {
        const int rp = u & 15;
        const int cq = u >> 4;
        const size_t ra = (size_t)(r0 + 2 * rp) * ALG_DIM + 4 * cq;
        const float4 xa = *reinterpret_cast<const float4*>(x + ra);
        const float4 xb = *reinterpret_cast<const float4*>(x + ra + ALG_DIM);
        const float4 ya = *reinterpret_cast<const float4*>(y + ra);
        const float4 yb = *reinterpret_cast<const float4*>(y + ra + ALG_DIM);
        const int pbase = (rp >> 2) * PLSTRIDE_DW + (rp & 3);
#define STG(d, XA, XB, YA, YB)                                                  \
        {                                                                       \
            const int dw = pbase + (4 * cq + (d)) * 4;                          \
            H2U hx; hx.h = __builtin_amdgcn_cvt_pkrtz(XA, XB);                  \
            H2U hy; hy.h = __builtin_amdgcn_cvt_pkrtz(YA, YB);                  \
            xs32[dw] = hx.u;                                                    \
            ys32[dw] = hy.u;                                                    \
        }
        STG(0, xa.x, xb.x, ya.x, yb.x)
        STG(1, xa.y, xb.y, ya.y, yb.y)
        STG(2, xa.z, xb.z, ya.z, yb.z)
        STG(3, xa.w, xb.w, ya.w, yb.w)
#undef STG
    }
    __syncthreads();

    const char* xsb = reinterpret_cast<const char*>(xs32) + q * PLSTRIDE_B;
    const char* ysb = reinterpret_cast<const char*>(ys32) + q * PLSTRIDE_B;

    if (act) {
        const int k = p;                     // identity (contiguous out columns)

        float a0 = 0.f, a1 = 0.f, a2 = 0.f, a3 = 0.f,
              a4 = 0.f, a5 = 0.f, a6 = 0.f, a7 = 0.f;

        const int nFull = sz >> 1;           // full uint4s (2 triples each)
        uint4 cur = prime;

#define PROC(PW, PC)                                                            \
        {                                                                       \
            const unsigned ox = (PW) & 0xFFFFu;                                 \
            const unsigned oy = (PW) >> 16;                                     \
            const uint4 wx = *reinterpret_cast<const uint4*>(xsb + ox);         \
            const uint4 wy = *reinterpret_cast<const uint4*>(ysb + oy);         \
            H2U cc; cc.u = (PC);                                                \
            H2U ux, uy;                                                         \
            ux.u = wx.x; uy.u = wy.x; c0 = (ux.h * uy.h) * cc.h + c0;           \
            ux.u = wx.y; uy.u = wy.y; c1 = (ux.h * uy.h) * cc.h + c1;           \
            ux.u = wx.z; uy.u = wy.z; c2 = (ux.h * uy.h) * cc.h + c2;           \
            ux.u = wx.w; uy.u = wy.w; c3 = (ux.h * uy.h) * cc.h + c3;           \
        }
#define FLUSH                                                                   \
        a0 += (float)c0.x; a1 += (float)c0.y;                                   \
        a2 += (float)c1.x; a3 += (float)c1.y;                                   \
        a4 += (float)c2.x; a5 += (float)c2.y;                                   \
        a6 += (float)c3.x; a7 += (float)c3.y;

        for (int chunk = 0; chunk < nFull; chunk += 16) {    // 32-triple window
            h2v c0 = (h2v)0.0f, c1 = (h2v)0.0f, c2 = (h2v)0.0f, c3 = (h2v)0.0f;
            const int hend = min(chunk + 16, nFull);
#pragma unroll 2
            for (int h = chunk; h < hend; ++h) {
                const uint4 nxt = tp[h + 1];  // prefetch; discarded at loop exit
                PROC(cur.x, cur.y)
                PROC(cur.z, cur.w)
                cur = nxt;
            }
            FLUSH
        }
        if (sz & 1) {                         // odd tail: cur == tp[nFull]
            h2v c0 = (h2v)0.0f, c1 = (h2v)0.0f, c2 = (h2v)0.0f, c3 = (h2v)0.0f;
            PROC(cur.x, cur.y)                // .z/.w of cur never touched
            FLUSH
        }
#undef FLUSH
#undef PROC

        const int rbase = r0 + (q << 3);
        out[(size_t)(rbase + 0) * ALG_DIM + k] = alpha * a0;
        out[(size_t)(rbase + 1) * ALG_DIM + k] = alpha * a1;
        out[(size_t)(rbase + 2) * ALG_DIM + k] = alpha * a2;
        out[(size_t)(rbase + 3) * ALG_DIM + k] = alpha * a3;
        out[(size_t)(rbase + 4) * ALG_DIM + k] = alpha * a4;
        out[(size_t)(rbase + 5) * ALG_DIM + k] = alpha * a5;
        out[(size_t)(rbase + 6) * ALG_DIM + k] = alpha * a6;
        out[(size_t)(rbase + 7) * ALG_DIM + k] = alpha * a7;
    }
}

// ---------- launch: 3 nodes (memset is 16 KB cnt only) ----------

extern "C" void kernel_launch(void* const* d_in, const int* in_sizes, int n_in,
                              void* d_out, int out_size, void* d_ws, size_t ws_size,
                              hipStream_t stream) {
    const float* x      = (const float*)d_in[0];
    const float* y      = (const float*)d_in[1];
    const int*   idx_i  = (const int*)d_in[2];
    const int*   idx_j  = (const int*)d_in[3];
    const int*   idx_k  = (const int*)d_in[4];
    const float* coeff  = (const float*)d_in[5];
    const float* alpha  = (const float*)d_in[6];
    float*       out    = (float*)d_out;

    const int nnz   = in_sizes[2];
    const int batch = in_sizes[0] / ALG_DIM;

    // ws: [cnt @0, 16 KB][packed @16384, 248*256*8 = 507904 B, no zero-init]
    char*  ws     = (char*)d_ws;
    int*   cnt    = (int*)ws;
    uint2* packed = (uint2*)(ws + 16384);

    hipMemsetAsync(ws, 0, 16384, stream);                   // cnt only

    const int sblk = ((nnz + 3) / 4 + 255) / 256;           // 4 triples/thread
    k_scatter<<<sblk, 256, 0, stream>>>(idx_i, idx_j, idx_k, coeff,
                                        cnt, packed, nnz);

    dim3 grid(batch / ROWS, KSPLIT);
    k_main<<<grid, 256, 0, stream>>>(x, y, (const uint4*)packed, cnt, alpha, out);
}